// Round 12
// baseline (4046.629 us; speedup 1.0000x reference)
//
#include <hip/hip_runtime.h>
#include <cstddef>

#define BB 256
#define TT 256
#define UU 512
#define MM 64
#define NT 512

typedef _Float16 h2 __attribute__((ext_vector_type(2)));
typedef unsigned int uint32;

#define NWTP (UU / 2 * UU)   // 131072 packed words (Wt)
#define NWWP (UU / 2 * MM)   // 16384 packed words (Ww)
#define NWRP (UU / 2 * MM)   // 16384 packed words (Wr cols 0..63)

__device__ __forceinline__ uint32 pkf(float lo, float hi) {
    h2 v; v[0] = (_Float16)lo; v[1] = (_Float16)hi;
    return __builtin_bit_cast(uint32, v);
}
__device__ __forceinline__ h2 toh2(uint32 u) { return __builtin_bit_cast(h2, u); }

// LDS-only barrier: LDS writes visible, global loads stay in flight.
__device__ __forceinline__ void bar() {
    asm volatile("s_waitcnt lgkmcnt(0)" ::: "memory");
    __builtin_amdgcn_s_barrier();
}
// Compiler-level fence: stops store-to-load forwarding / reordering of the
// same-wave LDS produce->consume pairs (HW DS ops are wave-ordered; we only
// need to stop the COMPILER from forwarding across the racy-looking pair).
__device__ __forceinline__ void cfence() {
    asm volatile("" ::: "memory");
}

// One-time weight repack into d_ws (same as round 10).
__global__ void cvt_kernel(const float* __restrict__ Wt,
                           const float* __restrict__ Wr,
                           const float* __restrict__ Ww,
                           uint32* __restrict__ Wtp,
                           uint32* __restrict__ Wwp,
                           uint32* __restrict__ Wrp) {
    int i = blockIdx.x * blockDim.x + threadIdx.x;
    const int n = NWTP + NWWP + NWRP;
    for (; i < n; i += gridDim.x * blockDim.x) {
        if (i < NWTP) {
            int k2 = i >> 9, r = i & 511;
            int jj = r >> 3, c = r & 7;
            int col = (c < 4) ? (jj * 4 + c) : (256 + jj * 4 + (c - 4));
            Wtp[i] = pkf(Wt[(size_t)(2 * k2) * UU + col],
                         Wt[(size_t)(2 * k2 + 1) * UU + col]);
        } else if (i < NWTP + NWWP) {
            int j = i - NWTP;
            int k2 = j >> 6, jj = j & 63;
            Wwp[j] = pkf(Ww[(size_t)(2 * k2) * MM + jj],
                         Ww[(size_t)(2 * k2 + 1) * MM + jj]);
        } else {
            int j = i - NWTP - NWWP;
            int k2 = j >> 6, jj = j & 63;
            Wrp[j] = pkf(Wr[(size_t)(2 * k2) * 65 + jj],
                         Wr[(size_t)(2 * k2 + 1) * 65 + jj]);
        }
    }
}

// 256 blocks x 512 threads, 1 batch/block, no grid sync.
// Wt half in registers, Wrp+Wwp in LDS (staged once). Redundant per-wave
// softmax/sigmoid (no 1-wave idle phases); rw64 kept in REGISTERS (the
// conditional LDS broadcast was r11's miscompile). 6 lgkm-only barriers.
__global__ __launch_bounds__(NT, 1) void dnc_kernel(
    const float* __restrict__ x,      // [B,T,U]
    const float* __restrict__ mem0,   // [B, M*U]
    const float* __restrict__ Wr,     // [U, M+1]  (fp32, col-64 only)
    const float* __restrict__ br,     // [M+1]
    const float* __restrict__ bt,     // [U]
    const float* __restrict__ bw,     // [M]
    const uint32* __restrict__ Wtp,
    const uint32* __restrict__ Wwp,
    const uint32* __restrict__ Wrp,
    float* __restrict__ out)          // [B,T,U]
{
    const int tid = threadIdx.x;   // 0..511
    const int b   = blockIdx.x;
    const int w   = tid >> 6;      // wave 0..7 (k-chunk, 32 k-pairs each)
    const int jj  = tid & 63;      // lane
    const int ut  = tid;           // owned output column

    __shared__ __align__(16) uint32 Wwl[NWWP];      // 64 KB, persistent
    __shared__ __align__(16) uint32 Wrl[NWRP];      // 64 KB, persistent
    __shared__ __align__(16) float  pWt[8][UU];     // 16 KB k-split partials
    __shared__ __align__(16) float  p1[8][68];
    __shared__ __align__(16) float  p2[8][68];
    __shared__ __align__(16) float  pbuf[UU];
    __shared__ __align__(16) float  lds_rw[8][64];  // per-wave softmax slot
    __shared__ __align__(16) float  lds_ww[8][64];  // per-wave sigmoid slot
    __shared__ __align__(16) uint32 mean2[UU / 2];
    __shared__ __align__(16) uint32 att2[UU / 2];
    __shared__ __align__(16) uint32 tr2[UU / 2];

    const uint4* Wp4 = (const uint4*)Wtp;   // [k2][128] uint4 pairs

    // ---- one-time staging: Wwp/Wrp -> LDS (linear uint4 copy) ----
    {
        const uint4* s1 = (const uint4*)Wwp;
        const uint4* s2 = (const uint4*)Wrp;
        uint4* d1 = (uint4*)Wwl;
        uint4* d2 = (uint4*)Wrl;
#pragma unroll
        for (int i = 0; i < 8; ++i) {
            d1[tid + i * 512] = s1[tid + i * 512];
            d2[tid + i * 512] = s2[tid + i * 512];
        }
    }

    // ---- permanent register cache: Wt k-pairs [w*32, w*32+16) ----
    uint4 wtcL[16], wtcH[16];
#pragma unroll
    for (int i = 0; i < 16; ++i) {
        size_t base = (size_t)(w * 32 + i) * 128 + jj * 2;
        wtcL[i] = Wp4[base];
        wtcH[i] = Wp4[base + 1];
    }

    float memc[MM];
#pragma unroll
    for (int m = 0; m < MM; ++m)
        memc[m] = mem0[(size_t)b * (MM * UU) + (size_t)m * UU + ut];

    const float btv  = bt[ut];
    const float wr64 = Wr[(size_t)ut * 65 + 64];
    const float bw_j = bw[jj];
    const float br_j = br[jj];
    const float br64 = br[64];

    float tr_prev = 0.f;
    float xv = x[(size_t)b * TT * UU + ut];

    __syncthreads();   // staging visible (outside hot loop, full drain OK)

    for (int t = 0; t < TT; ++t) {
        // ---- write weights of t-1 (Ww from LDS), mem update ----
        if (t > 0) {
            {
                float pa = 0.f;
#pragma unroll 8
                for (int kp = 0; kp < 32; ++kp)
                    pa = __builtin_amdgcn_fdot2(toh2(Wwl[(w * 32 + kp) * 64 + jj]),
                                                toh2(tr2[w * 32 + kp]), pa, false);
                p2[w][jj] = pa;
            }
            bar();
            // redundant per-wave sigmoid into own slot
            {
                float s = bw_j;
#pragma unroll
                for (int q = 0; q < 8; ++q) s += p2[q][jj];
                lds_ww[w][jj] = 1.f / (1.f + __expf(-s));
            }
            cfence();   // same-wave LDS produce->consume (HW wave-ordered)
#pragma unroll
            for (int q = 0; q < 16; ++q) {
                float4 wv = *(const float4*)&lds_ww[w][q * 4];   // own-wave bcast
                memc[q*4+0] = (1.f - wv.x) * memc[q*4+0] + wv.x * tr_prev;
                memc[q*4+1] = (1.f - wv.y) * memc[q*4+1] + wv.y * tr_prev;
                memc[q*4+2] = (1.f - wv.z) * memc[q*4+2] + wv.z * tr_prev;
                memc[q*4+3] = (1.f - wv.w) * memc[q*4+3] + wv.w * tr_prev;
            }
        }

        // ---- mean over M+1 rows, pack to h2 ----
        {
            float colsum = 0.f;
#pragma unroll
            for (int m = 0; m < MM; ++m) colsum += memc[m];
            float meanv = (colsum + xv) * (1.f / 65.f);
            pbuf[ut] = meanv * wr64;
            float mn = __shfl_down(meanv, 1, 64);
            if ((ut & 1) == 0) mean2[ut >> 1] = pkf(meanv, mn);
        }
        bar();

        // ---- read-GEMV: logits partials (cols 0..63), Wr from LDS ----
        {
            float pr = 0.f;
#pragma unroll 8
            for (int kp = 0; kp < 32; ++kp)
                pr = __builtin_amdgcn_fdot2(toh2(Wrl[(w * 32 + kp) * 64 + jj]),
                                            toh2(mean2[w * 32 + kp]), pr, false);
            p1[w][jj] = pr;
        }
        bar();

        // ---- redundant per-wave softmax over 65; rw64 stays in REGISTERS ----
        float rw64;
        {
            float lj = br_j;
#pragma unroll
            for (int q = 0; q < 8; ++q) lj += p1[q][jj];
            float4 pa4 = *(const float4*)&pbuf[jj * 8];
            float4 pb4 = *(const float4*)&pbuf[jj * 8 + 4];
            float s64 = pa4.x + pa4.y + pa4.z + pa4.w
                      + pb4.x + pb4.y + pb4.z + pb4.w;
#pragma unroll
            for (int o = 32; o >= 1; o >>= 1) s64 += __shfl_xor(s64, o, 64);
            float l64 = s64 + br64;
            float mx = fmaxf(lj, l64);
#pragma unroll
            for (int o = 32; o >= 1; o >>= 1) mx = fmaxf(mx, __shfl_xor(mx, o, 64));
            float e = __expf(lj - mx);
            float e64 = __expf(l64 - mx);
            float sm = e;
#pragma unroll
            for (int o = 32; o >= 1; o >>= 1) sm += __shfl_xor(sm, o, 64);
            sm += e64;
            lds_rw[w][jj] = e / sm;     // per-lane value, all 64 lanes write
            rw64 = e64 / sm;            // register broadcast (every lane has it)
        }
        cfence();   // same-wave LDS produce->consume

        // ---- attended (own-wave rw), pack to h2 ----
        {
            float att = rw64 * xv;
#pragma unroll
            for (int q = 0; q < 16; ++q) {
                float4 rv = *(const float4*)&lds_rw[w][q * 4];   // own-wave bcast
                att += rv.x * memc[q*4+0] + rv.y * memc[q*4+1]
                     + rv.z * memc[q*4+2] + rv.w * memc[q*4+3];
            }
            float an = __shfl_down(att, 1, 64);
            if ((ut & 1) == 0) att2[ut >> 1] = pkf(att, an);
        }
        bar();

        // ---- Wt GEMV: 16 cached kp (regs) + 16 streamed kp (pipelined) ----
        {
            float acc[8];
#pragma unroll
            for (int c = 0; c < 8; ++c) acc[c] = 0.f;

            auto dot8 = [&](const uint4& L, const uint4& H, h2 a) {
                acc[0] = __builtin_amdgcn_fdot2(toh2(L.x), a, acc[0], false);
                acc[1] = __builtin_amdgcn_fdot2(toh2(L.y), a, acc[1], false);
                acc[2] = __builtin_amdgcn_fdot2(toh2(L.z), a, acc[2], false);
                acc[3] = __builtin_amdgcn_fdot2(toh2(L.w), a, acc[3], false);
                acc[4] = __builtin_amdgcn_fdot2(toh2(H.x), a, acc[4], false);
                acc[5] = __builtin_amdgcn_fdot2(toh2(H.y), a, acc[5], false);
                acc[6] = __builtin_amdgcn_fdot2(toh2(H.z), a, acc[6], false);
                acc[7] = __builtin_amdgcn_fdot2(toh2(H.w), a, acc[7], false);
            };

            const uint4* sp = Wp4 + (size_t)(w * 32 + 16) * 128 + jj * 2;

            // issue group 0 (kp 16..19) BEFORE the long cached compute
            uint4 s[8];
#pragma unroll
            for (int i = 0; i < 4; ++i) {
                s[2*i]   = sp[(size_t)i * 128];
                s[2*i+1] = sp[(size_t)i * 128 + 1];
            }

            // cached half: 128 pure-register dot2s hide group-0 latency
#pragma unroll
            for (int i = 0; i < 16; ++i)
                dot8(wtcL[i], wtcH[i], toh2(att2[w * 32 + i]));

            // streamed groups: consume g, then issue g+1
#pragma unroll
            for (int g = 0; g < 4; ++g) {
#pragma unroll
                for (int i = 0; i < 4; ++i)
                    dot8(s[2*i], s[2*i+1], toh2(att2[w * 32 + 16 + g * 4 + i]));
                if (g < 3) {
#pragma unroll
                    for (int i = 0; i < 4; ++i) {
                        s[2*i]   = sp[(size_t)((g + 1) * 4 + i) * 128];
                        s[2*i+1] = sp[(size_t)((g + 1) * 4 + i) * 128 + 1];
                    }
                }
            }

            *(float4*)&pWt[w][jj * 4]       = make_float4(acc[0], acc[1], acc[2], acc[3]);
            *(float4*)&pWt[w][256 + jj * 4] = make_float4(acc[4], acc[5], acc[6], acc[7]);
        }
        bar();

        // ---- reduce 8 partials, relu, store, pack tr2 ----
        {
            float s = 0.f;
#pragma unroll
            for (int q = 0; q < 8; ++q) s += pWt[q][ut];
            float tr = fmaxf(s + btv, 0.f);
            tr_prev = tr;
            out[(size_t)b * TT * UU + (size_t)t * UU + ut] = tr;
            float trn = __shfl_down(tr, 1, 64);
            if ((ut & 1) == 0) tr2[ut >> 1] = pkf(tr, trn);
        }

        // prefetch next x (register only)
        {
            int tn = (t + 1 < TT) ? t + 1 : t;
            xv = x[(size_t)b * TT * UU + (size_t)tn * UU + ut];
        }
        bar();   // tr2 visible for next step's write-GEMV
    }
}

extern "C" void kernel_launch(void* const* d_in, const int* in_sizes, int n_in,
                              void* d_out, int out_size, void* d_ws, size_t ws_size,
                              hipStream_t stream) {
    const float* x    = (const float*)d_in[0];
    const float* mem0 = (const float*)d_in[1];
    const float* Wr   = (const float*)d_in[2];
    const float* br   = (const float*)d_in[3];
    const float* Wt   = (const float*)d_in[4];
    const float* bt   = (const float*)d_in[5];
    const float* Ww   = (const float*)d_in[6];
    const float* bw   = (const float*)d_in[7];
    float* out = (float*)d_out;

    uint32* Wtp = (uint32*)d_ws;          // [NWTP]
    uint32* Wwp = Wtp + NWTP;             // [NWWP]
    uint32* Wrp = Wwp + NWWP;             // [NWRP]

    cvt_kernel<<<dim3(256), dim3(256), 0, stream>>>(Wt, Wr, Ww, Wtp, Wwp, Wrp);
    dnc_kernel<<<dim3(BB), dim3(NT), 0, stream>>>(
        x, mem0, Wr, br, bt, bw, Wtp, Wwp, Wrp, out);
}

// Round 13
// 1558.269 us; speedup vs baseline: 2.5969x; 2.5969x over previous
//
#include <hip/hip_runtime.h>
#include <cstddef>

#define BB 256
#define TT 256
#define UU 512
#define MM 64
#define NT 512

typedef _Float16 h2 __attribute__((ext_vector_type(2)));
typedef unsigned int uint32;

#define NWTP (UU / 2 * UU)   // 131072 packed words (Wt)
#define NWWP (UU / 2 * MM)   // 16384 packed words (Ww)
#define NWRP (UU / 2 * MM)   // 16384 packed words (Wr cols 0..63)

__device__ __forceinline__ uint32 pkf(float lo, float hi) {
    h2 v; v[0] = (_Float16)lo; v[1] = (_Float16)hi;
    return __builtin_bit_cast(uint32, v);
}
__device__ __forceinline__ h2 toh2(uint32 u) { return __builtin_bit_cast(h2, u); }

// LDS-only barrier: LDS writes visible, global loads stay in flight.
__device__ __forceinline__ void bar() {
    asm volatile("s_waitcnt lgkmcnt(0)" ::: "memory");
    __builtin_amdgcn_s_barrier();
}
// Compiler fence for same-wave LDS produce->consume (HW DS is wave-ordered).
__device__ __forceinline__ void cfence() {
    asm volatile("" ::: "memory");
}

// One-time weight repack into d_ws (same as round 10).
__global__ void cvt_kernel(const float* __restrict__ Wt,
                           const float* __restrict__ Wr,
                           const float* __restrict__ Ww,
                           uint32* __restrict__ Wtp,
                           uint32* __restrict__ Wwp,
                           uint32* __restrict__ Wrp) {
    int i = blockIdx.x * blockDim.x + threadIdx.x;
    const int n = NWTP + NWWP + NWRP;
    for (; i < n; i += gridDim.x * blockDim.x) {
        if (i < NWTP) {
            int k2 = i >> 9, r = i & 511;
            int jj = r >> 3, c = r & 7;
            int col = (c < 4) ? (jj * 4 + c) : (256 + jj * 4 + (c - 4));
            Wtp[i] = pkf(Wt[(size_t)(2 * k2) * UU + col],
                         Wt[(size_t)(2 * k2 + 1) * UU + col]);
        } else if (i < NWTP + NWWP) {
            int j = i - NWTP;
            int k2 = j >> 6, jj = j & 63;
            Wwp[j] = pkf(Ww[(size_t)(2 * k2) * MM + jj],
                         Ww[(size_t)(2 * k2 + 1) * MM + jj]);
        } else {
            int j = i - NWTP - NWWP;
            int k2 = j >> 6, jj = j & 63;
            Wrp[j] = pkf(Wr[(size_t)(2 * k2) * 65 + jj],
                         Wr[(size_t)(2 * k2 + 1) * 65 + jj]);
        }
    }
}

// 256 blocks x 512 threads, 1 batch/block, no grid sync.
// Wt half in registers (r10-style streamed other half — NO hand pipeline,
// that spilled in r12), Wrp+Wwp in LDS (staged once). Redundant per-wave
// softmax/sigmoid; rw64 in registers. 6 lgkm-only barriers/step.
__global__ __launch_bounds__(NT, 1) void dnc_kernel(
    const float* __restrict__ x,      // [B,T,U]
    const float* __restrict__ mem0,   // [B, M*U]
    const float* __restrict__ Wr,     // [U, M+1]  (fp32, col-64 only)
    const float* __restrict__ br,     // [M+1]
    const float* __restrict__ bt,     // [U]
    const float* __restrict__ bw,     // [M]
    const uint32* __restrict__ Wtp,
    const uint32* __restrict__ Wwp,
    const uint32* __restrict__ Wrp,
    float* __restrict__ out)          // [B,T,U]
{
    const int tid = threadIdx.x;   // 0..511
    const int b   = blockIdx.x;
    const int w   = tid >> 6;      // wave 0..7 (k-chunk, 32 k-pairs each)
    const int jj  = tid & 63;      // lane
    const int ut  = tid;           // owned output column

    __shared__ __align__(16) uint32 Wwl[NWWP];      // 64 KB, persistent
    __shared__ __align__(16) uint32 Wrl[NWRP];      // 64 KB, persistent
    __shared__ __align__(16) float  pWt[8][UU];     // 16 KB k-split partials
    __shared__ __align__(16) float  p1[8][68];
    __shared__ __align__(16) float  p2[8][68];
    __shared__ __align__(16) float  pbuf[UU];
    __shared__ __align__(16) float  lds_rw[8][64];  // per-wave softmax slot
    __shared__ __align__(16) float  lds_ww[8][64];  // per-wave sigmoid slot
    __shared__ __align__(16) uint32 mean2[UU / 2];
    __shared__ __align__(16) uint32 att2[UU / 2];
    __shared__ __align__(16) uint32 tr2[UU / 2];

    const uint4* Wp4 = (const uint4*)Wtp;   // [k2][128] uint4 pairs

    // ---- one-time staging: Wwp/Wrp -> LDS (linear uint4 copy) ----
    {
        const uint4* s1 = (const uint4*)Wwp;
        const uint4* s2 = (const uint4*)Wrp;
        uint4* d1 = (uint4*)Wwl;
        uint4* d2 = (uint4*)Wrl;
#pragma unroll
        for (int i = 0; i < 8; ++i) {
            d1[tid + i * 512] = s1[tid + i * 512];
            d2[tid + i * 512] = s2[tid + i * 512];
        }
    }

    // ---- permanent register cache: Wt k-pairs [w*32, w*32+16) ----
    uint4 wtcL[16], wtcH[16];
#pragma unroll
    for (int i = 0; i < 16; ++i) {
        size_t base = (size_t)(w * 32 + i) * 128 + jj * 2;
        wtcL[i] = Wp4[base];
        wtcH[i] = Wp4[base + 1];
    }

    float memc[MM];
#pragma unroll
    for (int m = 0; m < MM; ++m)
        memc[m] = mem0[(size_t)b * (MM * UU) + (size_t)m * UU + ut];

    const float btv  = bt[ut];
    const float wr64 = Wr[(size_t)ut * 65 + 64];
    const float bw_j = bw[jj];
    const float br_j = br[jj];
    const float br64 = br[64];

    float tr_prev = 0.f;
    float xv = x[(size_t)b * TT * UU + ut];

    __syncthreads();   // staging visible (outside hot loop, full drain OK)

    for (int t = 0; t < TT; ++t) {
        // ---- write weights of t-1 (Ww from LDS), mem update ----
        if (t > 0) {
            {
                float pa = 0.f;
#pragma unroll 8
                for (int kp = 0; kp < 32; ++kp)
                    pa = __builtin_amdgcn_fdot2(toh2(Wwl[(w * 32 + kp) * 64 + jj]),
                                                toh2(tr2[w * 32 + kp]), pa, false);
                p2[w][jj] = pa;
            }
            bar();
            // redundant per-wave sigmoid into own slot
            {
                float s = bw_j;
#pragma unroll
                for (int q = 0; q < 8; ++q) s += p2[q][jj];
                lds_ww[w][jj] = 1.f / (1.f + __expf(-s));
            }
            cfence();
#pragma unroll
            for (int q = 0; q < 16; ++q) {
                float4 wv = *(const float4*)&lds_ww[w][q * 4];   // own-wave bcast
                memc[q*4+0] = (1.f - wv.x) * memc[q*4+0] + wv.x * tr_prev;
                memc[q*4+1] = (1.f - wv.y) * memc[q*4+1] + wv.y * tr_prev;
                memc[q*4+2] = (1.f - wv.z) * memc[q*4+2] + wv.z * tr_prev;
                memc[q*4+3] = (1.f - wv.w) * memc[q*4+3] + wv.w * tr_prev;
            }
        }

        // ---- mean over M+1 rows, pack to h2 ----
        {
            float colsum = 0.f;
#pragma unroll
            for (int m = 0; m < MM; ++m) colsum += memc[m];
            float meanv = (colsum + xv) * (1.f / 65.f);
            pbuf[ut] = meanv * wr64;
            float mn = __shfl_down(meanv, 1, 64);
            if ((ut & 1) == 0) mean2[ut >> 1] = pkf(meanv, mn);
        }
        bar();

        // ---- read-GEMV: logits partials (cols 0..63), Wr from LDS ----
        {
            float pr = 0.f;
#pragma unroll 8
            for (int kp = 0; kp < 32; ++kp)
                pr = __builtin_amdgcn_fdot2(toh2(Wrl[(w * 32 + kp) * 64 + jj]),
                                            toh2(mean2[w * 32 + kp]), pr, false);
            p1[w][jj] = pr;
        }
        bar();

        // ---- redundant per-wave softmax over 65; rw64 in REGISTERS ----
        float rw64;
        {
            float lj = br_j;
#pragma unroll
            for (int q = 0; q < 8; ++q) lj += p1[q][jj];
            float4 pa4 = *(const float4*)&pbuf[jj * 8];
            float4 pb4 = *(const float4*)&pbuf[jj * 8 + 4];
            float s64 = pa4.x + pa4.y + pa4.z + pa4.w
                      + pb4.x + pb4.y + pb4.z + pb4.w;
#pragma unroll
            for (int o = 32; o >= 1; o >>= 1) s64 += __shfl_xor(s64, o, 64);
            float l64 = s64 + br64;
            float mx = fmaxf(lj, l64);
#pragma unroll
            for (int o = 32; o >= 1; o >>= 1) mx = fmaxf(mx, __shfl_xor(mx, o, 64));
            float e = __expf(lj - mx);
            float e64 = __expf(l64 - mx);
            float sm = e;
#pragma unroll
            for (int o = 32; o >= 1; o >>= 1) sm += __shfl_xor(sm, o, 64);
            sm += e64;
            lds_rw[w][jj] = e / sm;     // per-lane value, all 64 lanes write
            rw64 = e64 / sm;            // every lane computes it -> register
        }
        cfence();

        // ---- attended (own-wave rw), pack to h2 ----
        {
            float att = rw64 * xv;
#pragma unroll
            for (int q = 0; q < 16; ++q) {
                float4 rv = *(const float4*)&lds_rw[w][q * 4];   // own-wave bcast
                att += rv.x * memc[q*4+0] + rv.y * memc[q*4+1]
                     + rv.z * memc[q*4+2] + rv.w * memc[q*4+3];
            }
            float an = __shfl_down(att, 1, 64);
            if ((ut & 1) == 0) att2[ut >> 1] = pkf(att, an);
        }
        bar();

        // ---- Wt GEMV: 16 streamed kp (r10 form) + 16 cached kp (regs) ----
        {
            float acc[8];
#pragma unroll
            for (int c = 0; c < 8; ++c) acc[c] = 0.f;

            auto dot8 = [&](const uint4& L, const uint4& H, h2 a) {
                acc[0] = __builtin_amdgcn_fdot2(toh2(L.x), a, acc[0], false);
                acc[1] = __builtin_amdgcn_fdot2(toh2(L.y), a, acc[1], false);
                acc[2] = __builtin_amdgcn_fdot2(toh2(L.z), a, acc[2], false);
                acc[3] = __builtin_amdgcn_fdot2(toh2(L.w), a, acc[3], false);
                acc[4] = __builtin_amdgcn_fdot2(toh2(H.x), a, acc[4], false);
                acc[5] = __builtin_amdgcn_fdot2(toh2(H.y), a, acc[5], false);
                acc[6] = __builtin_amdgcn_fdot2(toh2(H.z), a, acc[6], false);
                acc[7] = __builtin_amdgcn_fdot2(toh2(H.w), a, acc[7], false);
            };

            // streamed half (compiler pipelines the loads; no manual buffer)
            const uint4* sp = Wp4 + (size_t)(w * 32 + 16) * 128 + jj * 2;
#pragma unroll 4
            for (int i = 0; i < 16; ++i) {
                uint4 L = sp[(size_t)i * 128];
                uint4 H = sp[(size_t)i * 128 + 1];
                dot8(L, H, toh2(att2[w * 32 + 16 + i]));
            }
            // cached half: pure register dot2s
#pragma unroll
            for (int i = 0; i < 16; ++i)
                dot8(wtcL[i], wtcH[i], toh2(att2[w * 32 + i]));

            *(float4*)&pWt[w][jj * 4]       = make_float4(acc[0], acc[1], acc[2], acc[3]);
            *(float4*)&pWt[w][256 + jj * 4] = make_float4(acc[4], acc[5], acc[6], acc[7]);
        }
        bar();

        // ---- reduce 8 partials, relu, store, pack tr2 ----
        {
            float s = 0.f;
#pragma unroll
            for (int q = 0; q < 8; ++q) s += pWt[q][ut];
            float tr = fmaxf(s + btv, 0.f);
            tr_prev = tr;
            out[(size_t)b * TT * UU + (size_t)t * UU + ut] = tr;
            float trn = __shfl_down(tr, 1, 64);
            if ((ut & 1) == 0) tr2[ut >> 1] = pkf(tr, trn);
        }

        // prefetch next x (register only)
        {
            int tn = (t + 1 < TT) ? t + 1 : t;
            xv = x[(size_t)b * TT * UU + (size_t)tn * UU + ut];
        }
        bar();   // tr2 visible for next step's write-GEMV
    }
}

extern "C" void kernel_launch(void* const* d_in, const int* in_sizes, int n_in,
                              void* d_out, int out_size, void* d_ws, size_t ws_size,
                              hipStream_t stream) {
    const float* x    = (const float*)d_in[0];
    const float* mem0 = (const float*)d_in[1];
    const float* Wr   = (const float*)d_in[2];
    const float* br   = (const float*)d_in[3];
    const float* Wt   = (const float*)d_in[4];
    const float* bt   = (const float*)d_in[5];
    const float* Ww   = (const float*)d_in[6];
    const float* bw   = (const float*)d_in[7];
    float* out = (float*)d_out;

    uint32* Wtp = (uint32*)d_ws;          // [NWTP]
    uint32* Wwp = Wtp + NWTP;             // [NWWP]
    uint32* Wrp = Wwp + NWWP;             // [NWRP]

    cvt_kernel<<<dim3(256), dim3(256), 0, stream>>>(Wt, Wr, Ww, Wtp, Wwp, Wrp);
    dnc_kernel<<<dim3(BB), dim3(NT), 0, stream>>>(
        x, mem0, Wr, br, bt, bw, Wtp, Wwp, Wrp, out);
}